// Round 1
// baseline (347.433 us; speedup 1.0000x reference)
//
#include <hip/hip_runtime.h>
#include <cstdint>
#include <cstddef>

#define TOKENS 8192
#define DIN    4096
#define DOUT   4096
#define BM     128
#define BN     128
#define BK     64   // bytes of K per tile-step (int8 => 64 elements, one MFMA K)

typedef int   int4v   __attribute__((ext_vector_type(4)));

// ---------------------------------------------------------------------------
// Kernel 1: per-token dynamic quantization.
// One block per token row. Computes rowmax|x|, scale = max/127,
// x_q = clip(rint(x/scale), -127, 127) packed int8, and exact int row-sum.
// ---------------------------------------------------------------------------
__global__ __launch_bounds__(256) void quant_rows(const float* __restrict__ x,
                                                  int* __restrict__ xq,
                                                  float* __restrict__ ascale,
                                                  int* __restrict__ rsum) {
  const int row = blockIdx.x;
  const int t = threadIdx.x;
  const float4* xr = (const float4*)(x + (size_t)row * DIN);
  float4 v[4];
#pragma unroll
  for (int i = 0; i < 4; ++i) v[i] = xr[i * 256 + t];  // coalesced

  float m = 0.f;
#pragma unroll
  for (int i = 0; i < 4; ++i) {
    m = fmaxf(m, fabsf(v[i].x)); m = fmaxf(m, fabsf(v[i].y));
    m = fmaxf(m, fabsf(v[i].z)); m = fmaxf(m, fabsf(v[i].w));
  }
#pragma unroll
  for (int off = 32; off; off >>= 1) m = fmaxf(m, __shfl_xor(m, off));

  __shared__ float wmax[4];
  __shared__ int   wsum[4];
  const int lane = t & 63, wid = t >> 6;
  if (lane == 0) wmax[wid] = m;
  __syncthreads();
  m = fmaxf(fmaxf(wmax[0], wmax[1]), fmaxf(wmax[2], wmax[3]));

  const float s = m * (1.0f / 127.0f);
  const float sdiv = (m > 0.f) ? s : 1.0f;

  int ssum = 0;
#pragma unroll
  for (int i = 0; i < 4; ++i) {
    float q;
    q = fminf(fmaxf(rintf(v[i].x / sdiv), -127.f), 127.f); const int b0 = (int)q;
    q = fminf(fmaxf(rintf(v[i].y / sdiv), -127.f), 127.f); const int b1 = (int)q;
    q = fminf(fmaxf(rintf(v[i].z / sdiv), -127.f), 127.f); const int b2 = (int)q;
    q = fminf(fmaxf(rintf(v[i].w / sdiv), -127.f), 127.f); const int b3 = (int)q;
    ssum += b0 + b1 + b2 + b3;
    xq[(size_t)row * 1024 + i * 256 + t] =
        (b0 & 255) | ((b1 & 255) << 8) | ((b2 & 255) << 16) | ((b3 & 255) << 24);
  }
#pragma unroll
  for (int off = 32; off; off >>= 1) ssum += __shfl_xor(ssum, off);
  if (lane == 0) wsum[wid] = ssum;
  __syncthreads();
  if (t == 0) {
    rsum[row]   = wsum[0] + wsum[1] + wsum[2] + wsum[3];
    ascale[row] = s;
  }
}

// ---------------------------------------------------------------------------
// Kernel 2: weight int32 -> packed int8 (values already in [-127,127]).
// ---------------------------------------------------------------------------
__global__ __launch_bounds__(256) void wconv(const int* __restrict__ w,
                                             int* __restrict__ w8) {
  const int idx = blockIdx.x * 256 + threadIdx.x;   // one int4 (4 elems) each
  const int4 v = ((const int4*)w)[idx];
  w8[idx] = (v.x & 255) | ((v.y & 255) << 8) | ((v.z & 255) << 16) | ((v.w & 255) << 24);
}

// ---------------------------------------------------------------------------
// Kernel 3: int8 GEMM (m97 structure) + fused zp-correction/dequant/bias.
// C[t,o] = (sum_k xq[t,k]*w8[o,k] + rsum[t]*woff[o]) * ascale[t]*wscale[o] + bias[o]
// 128x128 tile, 4 waves (2x2 of 64x64), BK=64B, mfma_i32_16x16x64_i8.
// ---------------------------------------------------------------------------
__device__ __forceinline__ void gload_lds16(const char* g, char* l) {
  __builtin_amdgcn_global_load_lds(
      (const __attribute__((address_space(1))) void*)g,
      (__attribute__((address_space(3))) void*)l, 16, 0, 0);
}

__global__ __launch_bounds__(256) void gemm_i8(
    const char* __restrict__ xq, const char* __restrict__ w8,
    const float* __restrict__ ascale, const int* __restrict__ rsum,
    const float* __restrict__ wscale, const float* __restrict__ woff,
    const float* __restrict__ bias, float* __restrict__ y) {

  __shared__ __align__(16) char As[BM * BK];  // 8 KiB
  __shared__ __align__(16) char Bs[BN * BK];  // 8 KiB

  const int bid = blockIdx.x;
  const int ntn = DOUT / BN;             // 32
  const int tm = bid / ntn, tn = bid % ntn;
  const int t = threadIdx.x;
  const int lane = t & 63, wid = t >> 6;
  const int wm = (wid >> 1) * 64, wn = (wid & 1) * 64;

  int4v acc[4][4];
#pragma unroll
  for (int m = 0; m < 4; ++m)
#pragma unroll
    for (int n = 0; n < 4; ++n) acc[m][n] = (int4v){0, 0, 0, 0};

  // staging: thread t loads 16B of row (t>>2), byte offset (t&3)*16 within BK
  const char* ga = xq + (size_t)(tm * BM + (t >> 2)) * DIN + (t & 3) * 16;
  const char* gb = w8 + (size_t)(tn * BN + (t >> 2)) * DIN + (t & 3) * 16;
  char* la = As + t * 16;   // linear: wave-uniform base + lane*16
  char* lb = Bs + t * 16;

  const int frow = lane & 15;
  const int kx   = (lane >> 4) * 16;     // 16B k-chunk per lane group

  for (int kk = 0; kk < DIN; kk += BK) {
    gload_lds16(ga + kk,            la);
    gload_lds16(ga + kk + 64 * DIN, la + 4096);
    gload_lds16(gb + kk,            lb);
    gload_lds16(gb + kk + 64 * DIN, lb + 4096);
    __syncthreads();   // drains vmcnt -> LDS tiles complete & visible

    int4v a[4], b[4];
#pragma unroll
    for (int m = 0; m < 4; ++m)
      a[m] = *(const int4v*)(As + (wm + m * 16 + frow) * BK + kx);
#pragma unroll
    for (int n = 0; n < 4; ++n)
      b[n] = *(const int4v*)(Bs + (wn + n * 16 + frow) * BK + kx);

#pragma unroll
    for (int m = 0; m < 4; ++m)
#pragma unroll
      for (int n = 0; n < 4; ++n)
        acc[m][n] = __builtin_amdgcn_mfma_i32_16x16x64_i8(a[m], b[n], acc[m][n], 0, 0, 0);

    __syncthreads();   // all waves done reading before next overwrite
  }

  // epilogue: C/D layout col=lane&15, row=(lane>>4)*4+reg
  const int rbase = tm * BM + wm + (lane >> 4) * 4;
  const int cbase = tn * BN + wn + (lane & 15);
#pragma unroll
  for (int n = 0; n < 4; ++n) {
    const int col = cbase + n * 16;
    const float ws_ = wscale[col];
    const float wo_ = woff[col];
    const float bi_ = bias[col];
#pragma unroll
    for (int m = 0; m < 4; ++m) {
      const int r0 = rbase + m * 16;
#pragma unroll
      for (int j = 0; j < 4; ++j) {
        const int r = r0 + j;
        const float a = (float)acc[m][n][j] + (float)rsum[r] * wo_;
        y[(size_t)r * DOUT + col] = a * (ascale[r] * ws_) + bi_;
      }
    }
  }
}

// ---------------------------------------------------------------------------
extern "C" void kernel_launch(void* const* d_in, const int* in_sizes, int n_in,
                              void* d_out, int out_size, void* d_ws, size_t ws_size,
                              hipStream_t stream) {
  const float* x      = (const float*)d_in[0];
  const int*   w      = (const int*)  d_in[1];
  const float* wscale = (const float*)d_in[2];
  const float* woff   = (const float*)d_in[3];
  const float* bias   = (const float*)d_in[4];
  float* y = (float*)d_out;

  char* ws = (char*)d_ws;
  char*  xq     = ws;                                        // 33,554,432 B
  char*  w8     = ws + (size_t)TOKENS * DIN;                 // 16,777,216 B
  float* ascale = (float*)(w8 + (size_t)DOUT * DIN);         // 32,768 B
  int*   rsum   = (int*)(ascale + TOKENS);                   // 32,768 B

  hipLaunchKernelGGL(quant_rows, dim3(TOKENS), dim3(256), 0, stream,
                     x, (int*)xq, ascale, rsum);
  hipLaunchKernelGGL(wconv, dim3((DOUT * DIN / 4) / 256), dim3(256), 0, stream,
                     w, (int*)w8);
  hipLaunchKernelGGL(gemm_i8, dim3((TOKENS / BM) * (DOUT / BN)), dim3(256), 0, stream,
                     xq, w8, ascale, rsum, wscale, woff, bias, y);
}

// Round 2
// 263.093 us; speedup vs baseline: 1.3206x; 1.3206x over previous
//
#include <hip/hip_runtime.h>
#include <cstdint>
#include <cstddef>

#define TOKENS 8192
#define DIN    4096
#define DOUT   4096
#define BM     128
#define BN     128
#define BK     64   // bytes of K per tile-step (int8 => 64 elements, one MFMA K)

typedef int   int4v   __attribute__((ext_vector_type(4)));

// ---------------------------------------------------------------------------
// Kernel 1: per-token dynamic quantization.
// One block per token row. Computes rowmax|x|, scale = max/127,
// x_q = clip(rint(x/scale), -127, 127) packed int8, and exact int row-sum.
// ---------------------------------------------------------------------------
__global__ __launch_bounds__(256) void quant_rows(const float* __restrict__ x,
                                                  int* __restrict__ xq,
                                                  float* __restrict__ ascale,
                                                  int* __restrict__ rsum) {
  const int row = blockIdx.x;
  const int t = threadIdx.x;
  const float4* xr = (const float4*)(x + (size_t)row * DIN);
  float4 v[4];
#pragma unroll
  for (int i = 0; i < 4; ++i) v[i] = xr[i * 256 + t];  // coalesced

  float m = 0.f;
#pragma unroll
  for (int i = 0; i < 4; ++i) {
    m = fmaxf(m, fabsf(v[i].x)); m = fmaxf(m, fabsf(v[i].y));
    m = fmaxf(m, fabsf(v[i].z)); m = fmaxf(m, fabsf(v[i].w));
  }
#pragma unroll
  for (int off = 32; off; off >>= 1) m = fmaxf(m, __shfl_xor(m, off));

  __shared__ float wmax[4];
  __shared__ int   wsum[4];
  const int lane = t & 63, wid = t >> 6;
  if (lane == 0) wmax[wid] = m;
  __syncthreads();
  m = fmaxf(fmaxf(wmax[0], wmax[1]), fmaxf(wmax[2], wmax[3]));

  const float s = m * (1.0f / 127.0f);
  const float sdiv = (m > 0.f) ? s : 1.0f;

  int ssum = 0;
#pragma unroll
  for (int i = 0; i < 4; ++i) {
    float q;
    q = fminf(fmaxf(rintf(v[i].x / sdiv), -127.f), 127.f); const int b0 = (int)q;
    q = fminf(fmaxf(rintf(v[i].y / sdiv), -127.f), 127.f); const int b1 = (int)q;
    q = fminf(fmaxf(rintf(v[i].z / sdiv), -127.f), 127.f); const int b2 = (int)q;
    q = fminf(fmaxf(rintf(v[i].w / sdiv), -127.f), 127.f); const int b3 = (int)q;
    ssum += b0 + b1 + b2 + b3;
    xq[(size_t)row * 1024 + i * 256 + t] =
        (b0 & 255) | ((b1 & 255) << 8) | ((b2 & 255) << 16) | ((b3 & 255) << 24);
  }
#pragma unroll
  for (int off = 32; off; off >>= 1) ssum += __shfl_xor(ssum, off);
  if (lane == 0) wsum[wid] = ssum;
  __syncthreads();
  if (t == 0) {
    rsum[row]   = wsum[0] + wsum[1] + wsum[2] + wsum[3];
    ascale[row] = s;
  }
}

// ---------------------------------------------------------------------------
// Kernel 2: weight int32 -> packed int8 (values already in [-127,127]).
// ---------------------------------------------------------------------------
__global__ __launch_bounds__(256) void wconv(const int* __restrict__ w,
                                             int* __restrict__ w8) {
  const int idx = blockIdx.x * 256 + threadIdx.x;   // one int4 (4 elems) each
  const int4 v = ((const int4*)w)[idx];
  w8[idx] = (v.x & 255) | ((v.y & 255) << 8) | ((v.z & 255) << 16) | ((v.w & 255) << 24);
}

// ---------------------------------------------------------------------------
// Kernel 3: int8 GEMM + fused zp-correction/dequant/bias.
// T3 "minimum 2-phase": double-buffered LDS, next-tile global_load_lds issued
// BEFORE computing current tile; one vmcnt(0)+barrier per K-step.
// 128x128 tile, 4 waves (2x2 of 64x64), BK=64B, mfma_i32_16x16x64_i8.
// ---------------------------------------------------------------------------
__device__ __forceinline__ void gload_lds16(const char* g, char* l) {
  __builtin_amdgcn_global_load_lds(
      (const __attribute__((address_space(1))) void*)g,
      (__attribute__((address_space(3))) void*)l, 16, 0, 0);
}

__global__ __launch_bounds__(256, 4) void gemm_i8(
    const char* __restrict__ xq, const char* __restrict__ w8,
    const float* __restrict__ ascale, const int* __restrict__ rsum,
    const float* __restrict__ wscale, const float* __restrict__ woff,
    const float* __restrict__ bias, float* __restrict__ y) {

  // [buf][ A 8 KiB | B 8 KiB ] x 2 buffers = 32 KiB
  __shared__ __align__(16) char lds[2][16384];

  const int bid = blockIdx.x;
  const int ntn = DOUT / BN;             // 32
  const int tm = bid / ntn, tn = bid % ntn;
  const int t = threadIdx.x;
  const int lane = t & 63;
  const int wid = t >> 6;
  const int wm = (wid >> 1) * 64, wn = (wid & 1) * 64;

  int4v acc[4][4];
#pragma unroll
  for (int m = 0; m < 4; ++m)
#pragma unroll
    for (int n = 0; n < 4; ++n) acc[m][n] = (int4v){0, 0, 0, 0};

  // staging: thread t loads 16B of row (t>>2), byte chunk (t&3)*16 within BK
  const char* ga = xq + (size_t)(tm * BM + (t >> 2)) * DIN + (t & 3) * 16;
  const char* gb = w8 + (size_t)(tn * BN + (t >> 2)) * DIN + (t & 3) * 16;
  const int lofs = t * 16;               // linear LDS dest (wave-uniform + lane*16)

  const int frow = lane & 15;
  const int kx   = (lane >> 4) * 16;     // 16B k-chunk per lane group

  // prologue: stage tile 0 into buf 0
  {
    char* la = lds[0] + lofs;
    char* lb = lds[0] + 8192 + lofs;
    gload_lds16(ga, la);
    gload_lds16(ga + 64 * DIN, la + 4096);
    gload_lds16(gb, lb);
    gload_lds16(gb + 64 * DIN, lb + 4096);
  }
  __syncthreads();

  int cur = 0;
  for (int kk = 0; kk < DIN; kk += BK) {
    // prefetch next tile into the other buffer (in flight during compute)
    if (kk + BK < DIN) {
      char* la = lds[cur ^ 1] + lofs;
      char* lb = lds[cur ^ 1] + 8192 + lofs;
      gload_lds16(ga + kk + BK,            la);
      gload_lds16(ga + kk + BK + 64 * DIN, la + 4096);
      gload_lds16(gb + kk + BK,            lb);
      gload_lds16(gb + kk + BK + 64 * DIN, lb + 4096);
    }

    const char* As = lds[cur];
    const char* Bs = lds[cur] + 8192;

    int4v a[4], b[4];
#pragma unroll
    for (int m = 0; m < 4; ++m)
      a[m] = *(const int4v*)(As + (wm + m * 16 + frow) * BK + kx);
#pragma unroll
    for (int n = 0; n < 4; ++n)
      b[n] = *(const int4v*)(Bs + (wn + n * 16 + frow) * BK + kx);

#pragma unroll
    for (int m = 0; m < 4; ++m)
#pragma unroll
      for (int n = 0; n < 4; ++n)
        acc[m][n] = __builtin_amdgcn_mfma_i32_16x16x64_i8(a[m], b[n], acc[m][n], 0, 0, 0);

    // one barrier per K-step: drains this wave's ds_reads (lgkm) and the
    // prefetch loads (vmcnt) which had the whole compute phase to fly.
    __syncthreads();
    cur ^= 1;
  }

  // epilogue: C/D layout col=lane&15, row=(lane>>4)*4+reg
  const int rbase = tm * BM + wm + (lane >> 4) * 4;
  const int cbase = tn * BN + wn + (lane & 15);
#pragma unroll
  for (int n = 0; n < 4; ++n) {
    const int col = cbase + n * 16;
    const float ws_ = wscale[col];
    const float wo_ = woff[col];
    const float bi_ = bias[col];
#pragma unroll
    for (int m = 0; m < 4; ++m) {
      const int r0 = rbase + m * 16;
#pragma unroll
      for (int j = 0; j < 4; ++j) {
        const int r = r0 + j;
        const float a = (float)acc[m][n][j] + (float)rsum[r] * wo_;
        y[(size_t)r * DOUT + col] = a * (ascale[r] * ws_) + bi_;
      }
    }
  }
}

// ---------------------------------------------------------------------------
extern "C" void kernel_launch(void* const* d_in, const int* in_sizes, int n_in,
                              void* d_out, int out_size, void* d_ws, size_t ws_size,
                              hipStream_t stream) {
  const float* x      = (const float*)d_in[0];
  const int*   w      = (const int*)  d_in[1];
  const float* wscale = (const float*)d_in[2];
  const float* woff   = (const float*)d_in[3];
  const float* bias   = (const float*)d_in[4];
  float* y = (float*)d_out;

  char* ws = (char*)d_ws;
  char*  xq     = ws;                                        // 33,554,432 B
  char*  w8     = ws + (size_t)TOKENS * DIN;                 // 16,777,216 B
  float* ascale = (float*)(w8 + (size_t)DOUT * DIN);         // 32,768 B
  int*   rsum   = (int*)(ascale + TOKENS);                   // 32,768 B

  hipLaunchKernelGGL(quant_rows, dim3(TOKENS), dim3(256), 0, stream,
                     x, (int*)xq, ascale, rsum);
  hipLaunchKernelGGL(wconv, dim3((DOUT * DIN / 4) / 256), dim3(256), 0, stream,
                     w, (int*)w8);
  hipLaunchKernelGGL(gemm_i8, dim3((TOKENS / BM) * (DOUT / BN)), dim3(256), 0, stream,
                     xq, w8, ascale, rsum, wscale, woff, bias, y);
}

// Round 4
// 242.357 us; speedup vs baseline: 1.4336x; 1.0856x over previous
//
#include <hip/hip_runtime.h>
#include <cstdint>
#include <cstddef>

#define TOKENS 8192
#define DIN    4096
#define DOUT   4096

typedef int int4v __attribute__((ext_vector_type(4)));

// ---------------------------------------------------------------------------
// Kernel 1: per-token dynamic quantization (unchanged, near HBM-bound).
// ---------------------------------------------------------------------------
__global__ __launch_bounds__(256) void quant_rows(const float* __restrict__ x,
                                                  int* __restrict__ xq,
                                                  float* __restrict__ ascale,
                                                  int* __restrict__ rsum) {
  const int row = blockIdx.x;
  const int t = threadIdx.x;
  const float4* xr = (const float4*)(x + (size_t)row * DIN);
  float4 v[4];
#pragma unroll
  for (int i = 0; i < 4; ++i) v[i] = xr[i * 256 + t];

  float m = 0.f;
#pragma unroll
  for (int i = 0; i < 4; ++i) {
    m = fmaxf(m, fabsf(v[i].x)); m = fmaxf(m, fabsf(v[i].y));
    m = fmaxf(m, fabsf(v[i].z)); m = fmaxf(m, fabsf(v[i].w));
  }
#pragma unroll
  for (int off = 32; off; off >>= 1) m = fmaxf(m, __shfl_xor(m, off));

  __shared__ float wmax[4];
  __shared__ int   wsum[4];
  const int lane = t & 63, wid = t >> 6;
  if (lane == 0) wmax[wid] = m;
  __syncthreads();
  m = fmaxf(fmaxf(wmax[0], wmax[1]), fmaxf(wmax[2], wmax[3]));

  const float s = m * (1.0f / 127.0f);
  const float sdiv = (m > 0.f) ? s : 1.0f;

  int ssum = 0;
#pragma unroll
  for (int i = 0; i < 4; ++i) {
    float q;
    q = fminf(fmaxf(rintf(v[i].x / sdiv), -127.f), 127.f); const int b0 = (int)q;
    q = fminf(fmaxf(rintf(v[i].y / sdiv), -127.f), 127.f); const int b1 = (int)q;
    q = fminf(fmaxf(rintf(v[i].z / sdiv), -127.f), 127.f); const int b2 = (int)q;
    q = fminf(fmaxf(rintf(v[i].w / sdiv), -127.f), 127.f); const int b3 = (int)q;
    ssum += b0 + b1 + b2 + b3;
    xq[(size_t)row * 1024 + i * 256 + t] =
        (b0 & 255) | ((b1 & 255) << 8) | ((b2 & 255) << 16) | ((b3 & 255) << 24);
  }
#pragma unroll
  for (int off = 32; off; off >>= 1) ssum += __shfl_xor(ssum, off);
  if (lane == 0) wsum[wid] = ssum;
  __syncthreads();
  if (t == 0) {
    rsum[row]   = wsum[0] + wsum[1] + wsum[2] + wsum[3];
    ascale[row] = s;
  }
}

// ---------------------------------------------------------------------------
// Kernel 2: weight int32 -> packed int8 (unchanged).
// ---------------------------------------------------------------------------
__global__ __launch_bounds__(256) void wconv(const int* __restrict__ w,
                                             int* __restrict__ w8) {
  const int idx = blockIdx.x * 256 + threadIdx.x;
  const int4 v = ((const int4*)w)[idx];
  w8[idx] = (v.x & 255) | ((v.y & 255) << 8) | ((v.z & 255) << 16) | ((v.w & 255) << 24);
}

// ---------------------------------------------------------------------------
// Kernel 3: i8 GEMM, 256x256 tile, 8-phase schedule (T2+T3+T4+T5).
//  - 512 thr = 8 waves (2M x 4N), per-wave 128x64 C, mfma_i32_16x16x64_i8
//  - LDS 128 KiB: 4-buffer ring of K-tiles ([Aunit0|Aunit1|Bunit0|Bunit1] x 8KiB)
//  - prefetch depth 3 tiles; vmcnt(8) once per tile (never 0 in main loop)
//  - T2 swizzle (INVOLUTION, bits 4-5 only — no row-bit carry, self-inverse):
//      P(F) = F ^ (((F>>7)&3)<<4)   i.e.  col_phys = col ^ (((row>>1)&3)<<4)
//    Within a 16-lane ds_read_b128 group each (row&1, slot) bank-group gets
//    exactly 2 lanes -> free 2-way (was 8-way). Staging keeps the LDS dest
//    LINEAR and pre-permutes the GLOBAL source with the same involution.
// ---------------------------------------------------------------------------
__device__ __forceinline__ void gload_lds16(const char* g, char* l) {
  __builtin_amdgcn_global_load_lds(
      (const __attribute__((address_space(1))) void*)g,
      (__attribute__((address_space(3))) void*)l, 16, 0, 0);
}

#define MFMA_QUAD(MB)                                                         \
  _Pragma("unroll")                                                           \
  for (int m = 0; m < 4; ++m)                                                 \
    _Pragma("unroll")                                                         \
    for (int n = 0; n < 4; ++n)                                               \
      acc[m + MB][n] = __builtin_amdgcn_mfma_i32_16x16x64_i8(                 \
          a[m], bf[n], acc[m + MB][n], 0, 0, 0);

#define TILE_STEP(T_, DOSTAGE_, VMN_)                                         \
  do {                                                                        \
    const char* Lb = lds + ((T_) & 3) * 32768;                                \
    char* Wb = lds + (((T_) + 3) & 3) * 32768;                                \
    const size_t ko = (size_t)((T_) + 3) * 64;                                \
    int4v a[4], bf[4];                                                        \
    _Pragma("unroll")                                                         \
    for (int m = 0; m < 4; ++m)                                               \
      a[m] = *(const int4v*)(Lb + aoff + m * 1024);                           \
    _Pragma("unroll")                                                         \
    for (int n = 0; n < 4; ++n)                                               \
      bf[n] = *(const int4v*)(Lb + boff + n * 1024);                          \
    if (DOSTAGE_) {                                                           \
      gload_lds16(gA0 + ko, Wb + ldst);                                       \
      gload_lds16(gA1 + ko, Wb + 8192 + ldst);                                \
    }                                                                         \
    __builtin_amdgcn_s_barrier();                                             \
    __builtin_amdgcn_s_setprio(1);                                            \
    __builtin_amdgcn_sched_barrier(0);                                        \
    MFMA_QUAD(0)                                                              \
    __builtin_amdgcn_s_setprio(0);                                            \
    __builtin_amdgcn_s_barrier();                                             \
    _Pragma("unroll")                                                         \
    for (int m = 0; m < 4; ++m)                                               \
      a[m] = *(const int4v*)(Lb + aoff + (m + 4) * 1024);                     \
    if (DOSTAGE_) {                                                           \
      gload_lds16(gB0 + ko, Wb + 16384 + ldst);                               \
      gload_lds16(gB1 + ko, Wb + 24576 + ldst);                               \
    }                                                                         \
    __builtin_amdgcn_s_barrier();                                             \
    __builtin_amdgcn_s_setprio(1);                                            \
    __builtin_amdgcn_sched_barrier(0);                                        \
    MFMA_QUAD(4)                                                              \
    __builtin_amdgcn_s_setprio(0);                                            \
    if ((VMN_) == 8)      asm volatile("s_waitcnt vmcnt(8)" ::: "memory");    \
    else if ((VMN_) == 4) asm volatile("s_waitcnt vmcnt(4)" ::: "memory");    \
    else if ((VMN_) == 0) asm volatile("s_waitcnt vmcnt(0)" ::: "memory");    \
    __builtin_amdgcn_s_barrier();                                             \
  } while (0)

__global__ __launch_bounds__(512, 2) void gemm_i8(
    const char* __restrict__ xq, const char* __restrict__ w8,
    const float* __restrict__ ascale, const int* __restrict__ rsum,
    const float* __restrict__ wscale, const float* __restrict__ woff,
    const float* __restrict__ bias, float* __restrict__ y) {

  // 4 ring buffers x [Aunit0|Aunit1|Bunit0|Bunit1] x 8 KiB = 128 KiB
  __shared__ __align__(16) char lds[131072];

  const int bid = blockIdx.x;
  const int tm = bid >> 4;            // 32 M-tiles
  const int tn = bid & 15;            // 16 N-tiles
  const int t = threadIdx.x;          // 0..511
  const int lane = t & 63, wid = t >> 6;
  const int wmI = wid >> 2;           // 0..1 (M)
  const int wnI = wid & 3;            // 0..3 (N)

  // ---- staging source: involution P(L)=L^(((L>>7)&3)<<4) applied to L=t*16:
  //      row unchanged (t>>2); col chunk = (t&3) ^ ((t>>3)&3), 16B units.
  const int srow = t >> 2;                              // 0..127 within unit
  const int scol = ((t & 3) ^ ((t >> 3) & 3)) * 16;     // 0/16/32/48

  const char* gA0 = xq + (size_t)(tm * 256 + srow) * DIN + scol;
  const char* gA1 = gA0 + (size_t)128 * DIN;
  const char* gB0 = w8 + (size_t)(tn * 256 + srow) * DIN + scol;
  const char* gB1 = gB0 + (size_t)128 * DIN;
  const int ldst = t * 16;                              // LINEAR LDS dest

  // ---- fragment read offsets (same involution; mask ⊂ bits 4-5 so the add
  //      below never carries, and mask is constant across m,n sub-tiles) ----
  const int frow = lane & 15;
  const int swz  = ((lane >> 4) * 16) ^ (((frow >> 1) & 3) << 4);
  const int aoff = wmI * 8192 + frow * 64 + swz;                          // +m*1024
  const int boff = (2 + (wnI >> 1)) * 8192 + (wnI & 1) * 4096 + frow * 64 + swz; // +n*1024

  int4v acc[8][4];
#pragma unroll
  for (int m = 0; m < 8; ++m)
#pragma unroll
    for (int n = 0; n < 4; ++n) acc[m][n] = (int4v){0, 0, 0, 0};

  // ---- prologue: stage K-tiles 0,1,2 (12 loads/wave in flight) ----
#pragma unroll
  for (int p = 0; p < 3; ++p) {
    char* Wb = lds + p * 32768;
    gload_lds16(gA0 + p * 64, Wb + ldst);
    gload_lds16(gA1 + p * 64, Wb + 8192 + ldst);
    gload_lds16(gB0 + p * 64, Wb + 16384 + ldst);
    gload_lds16(gB1 + p * 64, Wb + 24576 + ldst);
  }
  asm volatile("s_waitcnt vmcnt(8)" ::: "memory");   // tile 0 landed
  __builtin_amdgcn_s_barrier();

  // ---- main loop: 64 K-tiles; stage t+3 during t; drain t+1 at tile end ----
  for (int T = 0; T < 61; ++T) TILE_STEP(T, true, 8);
  TILE_STEP(61, false, 4);
  TILE_STEP(62, false, 0);
  TILE_STEP(63, false, -1);

  // ---- epilogue: zp-correction + dequant + bias ----
  const int rb0 = tm * 256 + wmI * 128 + (lane >> 4) * 4;
  const int cb0 = tn * 256 + wnI * 64 + (lane & 15);
#pragma unroll
  for (int n = 0; n < 4; ++n) {
    const int col = cb0 + n * 16;
    const float ws_ = wscale[col];
    const float wo_ = woff[col];
    const float bi_ = bias[col];
#pragma unroll
    for (int m = 0; m < 8; ++m) {
      const int r0 = rb0 + m * 16;
#pragma unroll
      for (int j = 0; j < 4; ++j) {
        const int r = r0 + j;
        const float acf = (float)acc[m][n][j] + (float)rsum[r] * wo_;
        y[(size_t)r * DOUT + col] = acf * (ascale[r] * ws_) + bi_;
      }
    }
  }
}

// ---------------------------------------------------------------------------
extern "C" void kernel_launch(void* const* d_in, const int* in_sizes, int n_in,
                              void* d_out, int out_size, void* d_ws, size_t ws_size,
                              hipStream_t stream) {
  const float* x      = (const float*)d_in[0];
  const int*   w      = (const int*)  d_in[1];
  const float* wscale = (const float*)d_in[2];
  const float* woff   = (const float*)d_in[3];
  const float* bias   = (const float*)d_in[4];
  float* y = (float*)d_out;

  char* ws = (char*)d_ws;
  char*  xq     = ws;                                 // 33,554,432 B
  char*  w8     = ws + (size_t)TOKENS * DIN;          // 16,777,216 B
  float* ascale = (float*)(w8 + (size_t)DOUT * DIN);  // 32,768 B
  int*   rsum   = (int*)(ascale + TOKENS);            // 32,768 B

  hipLaunchKernelGGL(quant_rows, dim3(TOKENS), dim3(256), 0, stream,
                     x, (int*)xq, ascale, rsum);
  hipLaunchKernelGGL(wconv, dim3((DOUT * DIN / 4) / 256), dim3(256), 0, stream,
                     w, (int*)w8);
  hipLaunchKernelGGL(gemm_i8, dim3((TOKENS / 256) * (DOUT / 256)), dim3(512), 0, stream,
                     xq, w8, ascale, rsum, wscale, woff, bias, y);
}

// Round 5
// 198.319 us; speedup vs baseline: 1.7519x; 1.2221x over previous
//
#include <hip/hip_runtime.h>
#include <cstdint>
#include <cstddef>

#define TOKENS 8192
#define DIN    4096
#define DOUT   4096

typedef int int4v  __attribute__((ext_vector_type(4)));
typedef int int16v __attribute__((ext_vector_type(16)));

// ---------------------------------------------------------------------------
// Kernel 1: per-token dynamic quantization (unchanged, near HBM-bound).
// ---------------------------------------------------------------------------
__global__ __launch_bounds__(256) void quant_rows(const float* __restrict__ x,
                                                  int* __restrict__ xq,
                                                  float* __restrict__ ascale,
                                                  int* __restrict__ rsum) {
  const int row = blockIdx.x;
  const int t = threadIdx.x;
  const float4* xr = (const float4*)(x + (size_t)row * DIN);
  float4 v[4];
#pragma unroll
  for (int i = 0; i < 4; ++i) v[i] = xr[i * 256 + t];

  float m = 0.f;
#pragma unroll
  for (int i = 0; i < 4; ++i) {
    m = fmaxf(m, fabsf(v[i].x)); m = fmaxf(m, fabsf(v[i].y));
    m = fmaxf(m, fabsf(v[i].z)); m = fmaxf(m, fabsf(v[i].w));
  }
#pragma unroll
  for (int off = 32; off; off >>= 1) m = fmaxf(m, __shfl_xor(m, off));

  __shared__ float wmax[4];
  __shared__ int   wsum[4];
  const int lane = t & 63, wid = t >> 6;
  if (lane == 0) wmax[wid] = m;
  __syncthreads();
  m = fmaxf(fmaxf(wmax[0], wmax[1]), fmaxf(wmax[2], wmax[3]));

  const float s = m * (1.0f / 127.0f);
  const float sdiv = (m > 0.f) ? s : 1.0f;

  int ssum = 0;
#pragma unroll
  for (int i = 0; i < 4; ++i) {
    float q;
    q = fminf(fmaxf(rintf(v[i].x / sdiv), -127.f), 127.f); const int b0 = (int)q;
    q = fminf(fmaxf(rintf(v[i].y / sdiv), -127.f), 127.f); const int b1 = (int)q;
    q = fminf(fmaxf(rintf(v[i].z / sdiv), -127.f), 127.f); const int b2 = (int)q;
    q = fminf(fmaxf(rintf(v[i].w / sdiv), -127.f), 127.f); const int b3 = (int)q;
    ssum += b0 + b1 + b2 + b3;
    xq[(size_t)row * 1024 + i * 256 + t] =
        (b0 & 255) | ((b1 & 255) << 8) | ((b2 & 255) << 16) | ((b3 & 255) << 24);
  }
#pragma unroll
  for (int off = 32; off; off >>= 1) ssum += __shfl_xor(ssum, off);
  if (lane == 0) wsum[wid] = ssum;
  __syncthreads();
  if (t == 0) {
    rsum[row]   = wsum[0] + wsum[1] + wsum[2] + wsum[3];
    ascale[row] = s;
  }
}

// ---------------------------------------------------------------------------
// Kernel 2: weight int32 -> packed int8 (unchanged).
// ---------------------------------------------------------------------------
__global__ __launch_bounds__(256) void wconv(const int* __restrict__ w,
                                             int* __restrict__ w8) {
  const int idx = blockIdx.x * 256 + threadIdx.x;
  const int4 v = ((const int4*)w)[idx];
  w8[idx] = (v.x & 255) | ((v.y & 255) << 8) | ((v.z & 255) << 16) | ((v.w & 255) << 24);
}

// ---------------------------------------------------------------------------
// Kernel 3: i8 GEMM, 256x256 tile, pipelined 1-barrier-per-tile schedule.
//  - 512 thr = 8 waves (2M x 4N), per-wave 128x64 C, mfma_i32_32x32x32_i8
//    (acc 4x2 frags x 16 = 128 AGPRs; A/B: lane row=l&31, 16B chunk (l>>5)*16)
//  - LDS 128 KiB: 4-buffer ring; prefetch depth 3; vmcnt(8) per tile
//  - T2 involution swizzle (bits 4-5): col_phys = col ^ (((row>>1)&3)<<4);
//    LINEAR gload_lds dest + pre-permuted GLOBAL source (rule #21)
//  - per tile: stage T+3 | ds_read k1->regB | MFMA k0(regA) | vmcnt(8) |
//    lgkmcnt(0) | barrier | ds_read k0(T+1)->regA | MFMA k1(regB)
//    => ds_reads issue under MFMA pipe drain; LDS & MFMA pipes overlap.
// ---------------------------------------------------------------------------
__device__ __forceinline__ void gload_lds16(const char* g, char* l) {
  __builtin_amdgcn_global_load_lds(
      (const __attribute__((address_space(1))) void*)g,
      (__attribute__((address_space(3))) void*)l, 16, 0, 0);
}

#define MFMA8(AV, BV)                                                         \
  __builtin_amdgcn_s_setprio(1);                                              \
  _Pragma("unroll")                                                           \
  for (int mi = 0; mi < 4; ++mi)                                              \
    _Pragma("unroll")                                                         \
    for (int ni = 0; ni < 2; ++ni)                                            \
      acc[mi][ni] = __builtin_amdgcn_mfma_i32_32x32x32_i8(                    \
          AV[mi], BV[ni], acc[mi][ni], 0, 0, 0);                              \
  __builtin_amdgcn_s_setprio(0);

#define TILE_BODY(T_, STAGE_, VMN_, NEXT_)                                    \
  do {                                                                        \
    const char* Lb = lds + ((T_) & 3) * 32768;                                \
    char* Wb = lds + (((T_) + 3) & 3) * 32768;                                \
    if (STAGE_) {                                                             \
      const size_t ko = (size_t)((T_) + 3) * 64;                              \
      gload_lds16(gA0 + ko, Wb + ldst);                                       \
      gload_lds16(gA1 + ko, Wb + 8192 + ldst);                                \
      gload_lds16(gB0 + ko, Wb + 16384 + ldst);                               \
      gload_lds16(gB1 + ko, Wb + 24576 + ldst);                               \
    }                                                                         \
    _Pragma("unroll")                                                         \
    for (int mi = 0; mi < 4; ++mi)                                            \
      aB[mi] = *(const int4v*)(Lb + aoff1 + mi * 2048);                       \
    _Pragma("unroll")                                                         \
    for (int ni = 0; ni < 2; ++ni)                                            \
      bB[ni] = *(const int4v*)(Lb + boff1 + ni * 2048);                       \
    MFMA8(aA, bA)                                                             \
    if ((VMN_) >= 0) {                                                        \
      if ((VMN_) == 8)      asm volatile("s_waitcnt vmcnt(8)" ::: "memory");  \
      else if ((VMN_) == 4) asm volatile("s_waitcnt vmcnt(4)" ::: "memory");  \
      else                  asm volatile("s_waitcnt vmcnt(0)" ::: "memory");  \
      asm volatile("s_waitcnt lgkmcnt(0)" ::: "memory");                      \
      __builtin_amdgcn_s_barrier();                                           \
    }                                                                         \
    if (NEXT_) {                                                              \
      const char* Ln = lds + (((T_) + 1) & 3) * 32768;                        \
      _Pragma("unroll")                                                       \
      for (int mi = 0; mi < 4; ++mi)                                          \
        aA[mi] = *(const int4v*)(Ln + aoff0 + mi * 2048);                     \
      _Pragma("unroll")                                                       \
      for (int ni = 0; ni < 2; ++ni)                                          \
        bA[ni] = *(const int4v*)(Ln + boff0 + ni * 2048);                     \
    }                                                                         \
    MFMA8(aB, bB)                                                             \
  } while (0)

__global__ __launch_bounds__(512, 2) void gemm_i8(
    const char* __restrict__ xq, const char* __restrict__ w8,
    const float* __restrict__ ascale, const int* __restrict__ rsum,
    const float* __restrict__ wscale, const float* __restrict__ woff,
    const float* __restrict__ bias, float* __restrict__ y) {

  // 4 ring buffers x [Aunit0|Aunit1|Bunit0|Bunit1] x 8 KiB = 128 KiB
  __shared__ __align__(16) char lds[131072];

  const int bid = blockIdx.x;
  const int tm = bid >> 4;            // 32 M-tiles
  const int tn = bid & 15;            // 16 N-tiles
  const int t = threadIdx.x;          // 0..511
  const int lane = t & 63, wid = t >> 6;
  const int wmI = wid >> 2;           // 0..1 (M)
  const int wnI = wid & 3;            // 0..3 (N)

  // ---- staging source: involution P(L)=L^(((L>>7)&3)<<4) applied to L=t*16:
  const int srow = t >> 2;                              // 0..127 within unit
  const int scol = ((t & 3) ^ ((t >> 3) & 3)) * 16;     // 0/16/32/48

  const char* gA0 = xq + (size_t)(tm * 256 + srow) * DIN + scol;
  const char* gA1 = gA0 + (size_t)128 * DIN;
  const char* gB0 = w8 + (size_t)(tn * 256 + srow) * DIN + scol;
  const char* gB1 = gB0 + (size_t)128 * DIN;
  const int ldst = t * 16;                              // LINEAR LDS dest

  // ---- fragment read offsets (same involution; mask = row bits 1-2) ----
  const int mask  = ((lane >> 1) & 3) << 4;
  const int chunk = (lane >> 5) * 16;                   // k-chunk within 64B row
  const int aoff0 = wmI * 8192 + (lane & 31) * 64 + ((chunk +  0) ^ mask);
  const int aoff1 = wmI * 8192 + (lane & 31) * 64 + ((chunk + 32) ^ mask);
  const int bbase = (2 + (wnI >> 1)) * 8192 + (wnI & 1) * 4096 + (lane & 31) * 64;
  const int boff0 = bbase + ((chunk +  0) ^ mask);
  const int boff1 = bbase + ((chunk + 32) ^ mask);

  int16v acc[4][2];
#pragma unroll
  for (int mi = 0; mi < 4; ++mi)
#pragma unroll
    for (int ni = 0; ni < 2; ++ni)
#pragma unroll
      for (int rg = 0; rg < 16; ++rg) acc[mi][ni][rg] = 0;

  int4v aA[4], bA[2], aB[4], bB[2];

  // ---- prologue: stage K-tiles 0,1,2 (12 loads/wave in flight) ----
#pragma unroll
  for (int p = 0; p < 3; ++p) {
    char* Wb = lds + p * 32768;
    gload_lds16(gA0 + p * 64, Wb + ldst);
    gload_lds16(gA1 + p * 64, Wb + 8192 + ldst);
    gload_lds16(gB0 + p * 64, Wb + 16384 + ldst);
    gload_lds16(gB1 + p * 64, Wb + 24576 + ldst);
  }
  asm volatile("s_waitcnt vmcnt(8)" ::: "memory");   // tile 0 landed
  __builtin_amdgcn_s_barrier();
#pragma unroll
  for (int mi = 0; mi < 4; ++mi) aA[mi] = *(const int4v*)(lds + aoff0 + mi * 2048);
#pragma unroll
  for (int ni = 0; ni < 2; ++ni) bA[ni] = *(const int4v*)(lds + boff0 + ni * 2048);

  // ---- main loop: 64 K-tiles; stage t+3 during t; drain t+1 per tile ----
  for (int T = 0; T < 61; ++T) TILE_BODY(T, 1, 8, 1);
  TILE_BODY(61, 0, 4, 1);
  TILE_BODY(62, 0, 0, 1);
  TILE_BODY(63, 0, -1, 0);

  // ---- epilogue: zp-correction + dequant + bias ----
  // C/D 32x32: col = lane&31, row = (rg&3) + 8*(rg>>2) + 4*(lane>>5)
  const int rb0 = tm * 256 + wmI * 128 + 4 * (lane >> 5);
  const int cb0 = tn * 256 + wnI * 64 + (lane & 31);
  const float ws0 = wscale[cb0],      ws1 = wscale[cb0 + 32];
  const float wo0 = woff[cb0],        wo1 = woff[cb0 + 32];
  const float bi0 = bias[cb0],        bi1 = bias[cb0 + 32];
#pragma unroll
  for (int mi = 0; mi < 4; ++mi) {
#pragma unroll
    for (int rg = 0; rg < 16; ++rg) {
      const int r = rb0 + mi * 32 + (rg & 3) + 8 * (rg >> 2);
      const float as_ = ascale[r];
      const float rs_ = (float)rsum[r];
      y[(size_t)r * DOUT + cb0]      = ((float)acc[mi][0][rg] + rs_ * wo0) * (as_ * ws0) + bi0;
      y[(size_t)r * DOUT + cb0 + 32] = ((float)acc[mi][1][rg] + rs_ * wo1) * (as_ * ws1) + bi1;
    }
  }
}

// ---------------------------------------------------------------------------
extern "C" void kernel_launch(void* const* d_in, const int* in_sizes, int n_in,
                              void* d_out, int out_size, void* d_ws, size_t ws_size,
                              hipStream_t stream) {
  const float* x      = (const float*)d_in[0];
  const int*   w      = (const int*)  d_in[1];
  const float* wscale = (const float*)d_in[2];
  const float* woff   = (const float*)d_in[3];
  const float* bias   = (const float*)d_in[4];
  float* y = (float*)d_out;

  char* ws = (char*)d_ws;
  char*  xq     = ws;                                 // 33,554,432 B
  char*  w8     = ws + (size_t)TOKENS * DIN;          // 16,777,216 B
  float* ascale = (float*)(w8 + (size_t)DOUT * DIN);  // 32,768 B
  int*   rsum   = (int*)(ascale + TOKENS);            // 32,768 B

  hipLaunchKernelGGL(quant_rows, dim3(TOKENS), dim3(256), 0, stream,
                     x, (int*)xq, ascale, rsum);
  hipLaunchKernelGGL(wconv, dim3((DOUT * DIN / 4) / 256), dim3(256), 0, stream,
                     w, (int*)w8);
  hipLaunchKernelGGL(gemm_i8, dim3((TOKENS / 256) * (DOUT / 256)), dim3(512), 0, stream,
                     xq, w8, ascale, rsum, wscale, woff, bias, y);
}